// Round 4
// baseline (668.064 us; speedup 1.0000x reference)
//
#include <hip/hip_runtime.h>

typedef unsigned short u16;
typedef unsigned int u32;
typedef __bf16 bf16x8 __attribute__((ext_vector_type(8)));
typedef float f32x4 __attribute__((ext_vector_type(4)));

#define DI __device__ __forceinline__

DI u16 f2bf(float f) {
  union { float f; u32 u; } v; v.f = f;
  return (u16)((v.u + 0x7fffu + ((v.u >> 16) & 1u)) >> 16);
}
DI float bf2f(u16 h) {
  union { u32 u; float f; } v; v.u = ((u32)h) << 16;
  return v.f;
}
DI bf16x8 pack8(float4 a, float4 b) {
  union { bf16x8 v; u32 u[4]; } r;
  r.u[0] = (u32)f2bf(a.x) | ((u32)f2bf(a.y) << 16);
  r.u[1] = (u32)f2bf(a.z) | ((u32)f2bf(a.w) << 16);
  r.u[2] = (u32)f2bf(b.x) | ((u32)f2bf(b.y) << 16);
  r.u[3] = (u32)f2bf(b.z) | ((u32)f2bf(b.w) << 16);
  return r.v;
}

constexpr float INV_M = 1.0f / 32768.0f;  // 1/(B*C)

// ---------------- weight convert: 10 x [512,512] fp32 -> bf16 ----------------
__global__ void convw_k(const float* wa1, const float* wb1, const float* wu1, const float* wv1, const float* we1,
                        const float* wa2, const float* wb2, const float* wu2, const float* wv2, const float* we2,
                        u16* dst) {
  int idx = blockIdx.x * 256 + threadIdx.x;   // group of 4 floats
  int m = idx >> 16;
  int i = (idx & 0xffff) << 2;
  const float* s;
  switch (m) {
    case 0: s = wa1; break; case 1: s = wb1; break; case 2: s = wu1; break;
    case 3: s = wv1; break; case 4: s = we1; break; case 5: s = wa2; break;
    case 6: s = wb2; break; case 7: s = wu2; break; case 8: s = wv2; break;
    default: s = we2; break;
  }
  float4 v = *(const float4*)(s + i);
  ushort4 o;
  o.x = f2bf(v.x); o.y = f2bf(v.y); o.z = f2bf(v.z); o.w = f2bf(v.w);
  *(ushort4*)(dst + ((size_t)m << 18) + i) = o;
}

// ---------------- GEMM, no-LDS direct-MFMA: out[m,n] = sum_k A[m,k] * W[n,k] ----------------
// Block 256 thr = 4 waves: vm=wid&1 (rows), vn=wid>>1 (cols). Block tile 64x128, wave 32x64.
// A/B fragments loaded straight from global (lane l: row base+(l&15), k q*8 -> 16B), K-loop
// fully unrolled with 1-step register double-buffer; NO LDS, NO barriers in the K-loop.
// SWZ: 1-D grid, XCD-aware remap (4 cb of one rb -> same XCD for L2 A reuse).
// EPI==1: fp32 store. EPI==2: msg=acc+Vix+Vjx -> bf16 + fused edge BN stats.
template<int EPI, int ABF, int SWZ>
__global__ __launch_bounds__(256, 4) void gemm_k(
    const void* __restrict__ A_, const u16* __restrict__ W,
    float* __restrict__ outf, int ldout,
    u16* __restrict__ msg, const float* __restrict__ V4,
    float* __restrict__ esum, float* __restrict__ esq) {
  const int tid = threadIdx.x;
  const int lane = tid & 63, wid = tid >> 6;
  const int vm = wid & 1, vn = wid >> 1;
  const int q = lane >> 4, l15 = lane & 15;
  int rb, cb;
  if (SWZ) {
    int l = blockIdx.x;
    int xcd = l & 7, t = l >> 3;
    cb = t & 3;
    rb = ((t >> 2) << 3) | xcd;
    if (rb >= 729) return;
  } else {
    rb = blockIdx.y; cb = blockIdx.x;
  }

  // lane-private source pointers (k-offset q*8 baked in)
  const u16*   wp0 = W + ((size_t)(cb * 128 + vn * 64 + l15) << 9) + q * 8;
  const u16*   ab0 = (const u16*)A_  + ((size_t)(rb * 64 + vm * 32 + l15) << 9) + q * 8;
  const float* af0 = (const float*)A_ + ((size_t)(rb * 64 + vm * 32 + l15) << 9) + q * 8;

  f32x4 acc[2][4];
#pragma unroll
  for (int a = 0; a < 2; a++)
#pragma unroll
    for (int b = 0; b < 4; b++) acc[a][b] = (f32x4){0.f, 0.f, 0.f, 0.f};

  bf16x8 wc[4], wn_[4];
  bf16x8 ac[2], an_[2];
  float4 fc[2][2], fn[2][2];

#pragma unroll
  for (int nt = 0; nt < 4; nt++) wc[nt] = *(const bf16x8*)(wp0 + nt * 8192);
  if (ABF) {
#pragma unroll
    for (int mt = 0; mt < 2; mt++) ac[mt] = *(const bf16x8*)(ab0 + mt * 8192);
  } else {
#pragma unroll
    for (int mt = 0; mt < 2; mt++) {
      fc[mt][0] = *(const float4*)(af0 + mt * 8192);
      fc[mt][1] = *(const float4*)(af0 + mt * 8192 + 4);
    }
  }

#pragma unroll
  for (int ks = 0; ks < 16; ks++) {
    if (ks < 15) {
      const int ko = (ks + 1) * 32;
#pragma unroll
      for (int nt = 0; nt < 4; nt++) wn_[nt] = *(const bf16x8*)(wp0 + nt * 8192 + ko);
      if (ABF) {
#pragma unroll
        for (int mt = 0; mt < 2; mt++) an_[mt] = *(const bf16x8*)(ab0 + mt * 8192 + ko);
      } else {
#pragma unroll
        for (int mt = 0; mt < 2; mt++) {
          fn[mt][0] = *(const float4*)(af0 + mt * 8192 + ko);
          fn[mt][1] = *(const float4*)(af0 + mt * 8192 + ko + 4);
        }
      }
    }
    bf16x8 afr[2];
#pragma unroll
    for (int mt = 0; mt < 2; mt++)
      afr[mt] = ABF ? ac[mt] : pack8(fc[mt][0], fc[mt][1]);
#pragma unroll
    for (int mt = 0; mt < 2; mt++)
#pragma unroll
      for (int nt = 0; nt < 4; nt++)
        acc[mt][nt] = __builtin_amdgcn_mfma_f32_16x16x32_bf16(afr[mt], wc[nt], acc[mt][nt], 0, 0, 0);
    if (ks < 15) {
#pragma unroll
      for (int nt = 0; nt < 4; nt++) wc[nt] = wn_[nt];
      if (ABF) {
#pragma unroll
        for (int mt = 0; mt < 2; mt++) ac[mt] = an_[mt];
      } else {
#pragma unroll
        for (int mt = 0; mt < 2; mt++) { fc[mt][0] = fn[mt][0]; fc[mt][1] = fn[mt][1]; }
      }
    }
  }

  if (EPI == 1) {
#pragma unroll
    for (int mt = 0; mt < 2; mt++) {
      int grow0 = rb * 64 + vm * 32 + mt * 16 + q * 4;
#pragma unroll
      for (int nt = 0; nt < 4; nt++) {
        int gcol = cb * 128 + vn * 64 + nt * 16 + l15;
#pragma unroll
        for (int r = 0; r < 4; r++)
          outf[(size_t)(grow0 + r) * ldout + gcol] = acc[mt][nt][r];
      }
    }
  } else {
    // msg = acc + Vix[b,i,:] + Vjx[b,j,:]; row = b*729 + i*27 + j
    __shared__ float sm[256];
    float ms[2][4], m2[2][4];
#pragma unroll
    for (int mt = 0; mt < 2; mt++) {
#pragma unroll
      for (int r = 0; r < 4; r++) {
        int grow = rb * 64 + vm * 32 + mt * 16 + q * 4 + r;
        int b = grow / 729;
        int e = grow - b * 729;
        int i = e / 27;
        int j = e - i * 27;
        const float* vix = V4 + (((size_t)(b * 27 + i)) << 11);
        const float* vjx = V4 + (((size_t)(b * 27 + j)) << 11) + 512;
        u16* mrow = msg + (((size_t)grow) << 9);
        float s1 = 0.f, s2 = 0.f;
#pragma unroll
        for (int nt = 0; nt < 4; nt++) {
          int c = cb * 128 + vn * 64 + nt * 16 + l15;
          float m = acc[mt][nt][r] + vix[c] + vjx[c];
          mrow[c] = f2bf(m);
          s1 += m;
          s2 += m * m;
        }
        ms[mt][r] = s1;
        m2[mt][r] = s2;
      }
    }
#pragma unroll
    for (int msk = 1; msk < 16; msk <<= 1) {
#pragma unroll
      for (int mt = 0; mt < 2; mt++)
#pragma unroll
        for (int r = 0; r < 4; r++) {
          ms[mt][r] += __shfl_xor(ms[mt][r], msk);
          m2[mt][r] += __shfl_xor(m2[mt][r], msk);
        }
    }
    __syncthreads();
    if (l15 == 0) {
#pragma unroll
      for (int mt = 0; mt < 2; mt++)
#pragma unroll
        for (int r = 0; r < 4; r++) {
          int rib = vm * 32 + mt * 16 + q * 4 + r;
          sm[vn * 64 + rib] = ms[mt][r];
          sm[128 + vn * 64 + rib] = m2[mt][r];
        }
    }
    __syncthreads();
    if (tid < 64) {
      int grow = rb * 64 + tid;
      int e = grow % 729;
      atomicAdd(&esum[e], sm[tid] + sm[64 + tid]);
      atomicAdd(&esq[e], sm[128 + tid] + sm[192 + tid]);
    }
  }
}

// ---------------- fused: eab; eout = ein + relu(bn(msg)); sigmoid+softmax_j; agg; xnew; vstats ----------------
// 256 threads, 2 channels/thread, packed loads.
template<int INBF, int OUTBF>
__global__ __launch_bounds__(256) void edge_attn_k(
    const u16* __restrict__ msg, const void* __restrict__ ein_, void* __restrict__ eout_,
    const float* __restrict__ esum, const float* __restrict__ esq,
    const float* __restrict__ ge, const float* __restrict__ be,
    const float* __restrict__ V4,
    float* __restrict__ xnew, float* __restrict__ vsum, float* __restrict__ vsq) {
  const int bi = blockIdx.x;          // b*27 + i
  const int b = bi / 27, i = bi - b * 27;
  const int t = threadIdx.x;          // channels 2t, 2t+1
  __shared__ float2 sab[27];
  if (t < 27) {
    int e = i * 27 + t;
    float mean = esum[e] * INV_M;
    float var = esq[e] * INV_M - mean * mean;
    float a = ge[e] * rsqrtf(var + 1e-5f);
    sab[t] = make_float2(a, be[e] - mean * a);
  }
  __syncthreads();
  const size_t ebase = (((size_t)(b * 729 + i * 27)) << 9) + 2 * t;
  const u16* einb = (const u16*)ein_;
  const float* einf = (const float*)ein_;
  u16* eoutb = (u16*)eout_;
  float* eoutf = (float*)eout_;
  float t0[27], t1[27];
  float ss0 = 0.f, ss1 = 0.f;
#pragma unroll
  for (int j = 0; j < 27; j++) {
    size_t idx = ebase + (((size_t)j) << 9);
    float2 ab = sab[j];
    u32 mp = *(const u32*)(msg + idx);
    float2 ei;
    if (INBF) {
      u32 ep = *(const u32*)(einb + idx);
      ei = make_float2(bf2f((u16)ep), bf2f((u16)(ep >> 16)));
    } else {
      ei = *(const float2*)(einf + idx);
    }
    float e0 = ei.x + fmaxf(fmaf(ab.x, bf2f((u16)mp), ab.y), 0.f);
    float e1 = ei.y + fmaxf(fmaf(ab.x, bf2f((u16)(mp >> 16)), ab.y), 0.f);
    if (OUTBF) {
      *(u32*)(eoutb + idx) = (u32)f2bf(e0) | ((u32)f2bf(e1) << 16);
    } else {
      *(float2*)(eoutf + idx) = make_float2(e0, e1);
    }
    float x0 = __expf(1.f / (1.f + __expf(-e0)));
    float x1 = __expf(1.f / (1.f + __expf(-e1)));
    ss0 += x0; ss1 += x1;
    t0[j] = x0; t1[j] = x1;
  }
  float a0 = 0.f, a1 = 0.f;
#pragma unroll
  for (int j = 0; j < 27; j++) {
    float2 uj = *(const float2*)(V4 + (((size_t)(b * 27 + j)) << 11) + 1536 + 2 * t);  // Ujx
    a0 = fmaf(t0[j], uj.x, a0);
    a1 = fmaf(t1[j], uj.y, a1);
  }
  float2 ui = *(const float2*)(V4 + (((size_t)(b * 27 + i)) << 11) + 1024 + 2 * t);    // Uix
  float xn0 = ui.x + a0 / (ss0 * 27.f);
  float xn1 = ui.y + a1 / (ss1 * 27.f);
  *(float2*)(xnew + (((size_t)bi) << 9) + 2 * t) = make_float2(xn0, xn1);
  float v = xn0 + xn1, v2 = xn0 * xn0 + xn1 * xn1;
#pragma unroll
  for (int m = 32; m >= 1; m >>= 1) {
    v += __shfl_xor(v, m);
    v2 += __shfl_xor(v2, m);
  }
  __shared__ float red[8];
  int w = t >> 6, ln = t & 63;
  if (ln == 0) { red[w] = v; red[4 + w] = v2; }
  __syncthreads();
  if (t == 0) {
    float s1 = 0.f, s2 = 0.f;
#pragma unroll
    for (int k = 0; k < 4; k++) { s1 += red[k]; s2 += red[4 + k]; }
    atomicAdd(&vsum[i], s1);
    atomicAdd(&vsq[i], s2);
  }
}

// ---------------- x_out = relu(res + bn_v(xnew)), float4 ----------------
__global__ void vert_bn_k(const float4* __restrict__ xnew, const float4* __restrict__ res,
                          const float* __restrict__ vsum, const float* __restrict__ vsq,
                          const float* __restrict__ g, const float* __restrict__ bt,
                          float4* __restrict__ out) {
  int idx = blockIdx.x * 256 + threadIdx.x;   // float4 index, 221184 total
  int i = (idx >> 7) % 27;
  float mean = vsum[i] * INV_M;
  float var = vsq[i] * INV_M - mean * mean;
  float a = g[i] * rsqrtf(var + 1e-5f);
  float bb = bt[i] - mean * a;
  float4 xv = xnew[idx];
  float4 rv = res[idx];
  float4 o;
  o.x = fmaxf(rv.x + fmaf(a, xv.x, bb), 0.f);
  o.y = fmaxf(rv.y + fmaf(a, xv.y, bb), 0.f);
  o.z = fmaxf(rv.z + fmaf(a, xv.z, bb), 0.f);
  o.w = fmaxf(rv.w + fmaf(a, xv.w, bb), 0.f);
  out[idx] = o;
}

extern "C" void kernel_launch(void* const* d_in, const int* in_sizes, int n_in,
                              void* d_out, int out_size, void* d_ws, size_t ws_size,
                              hipStream_t stream) {
  const float* x    = (const float*)d_in[0];
  const float* edge = (const float*)d_in[1];
  const float* WU1 = (const float*)d_in[2];
  const float* WV1 = (const float*)d_in[3];
  const float* WA1 = (const float*)d_in[4];
  const float* WB1 = (const float*)d_in[5];
  const float* WE1 = (const float*)d_in[6];
  const float* WU2 = (const float*)d_in[7];
  const float* WV2 = (const float*)d_in[8];
  const float* WA2 = (const float*)d_in[9];
  const float* WB2 = (const float*)d_in[10];
  const float* WE2 = (const float*)d_in[11];
  const float* gv1 = (const float*)d_in[12];
  const float* bv1 = (const float*)d_in[13];
  const float* ge1 = (const float*)d_in[14];
  const float* be1 = (const float*)d_in[15];
  const float* gv2 = (const float*)d_in[16];
  const float* bv2 = (const float*)d_in[17];
  const float* ge2 = (const float*)d_in[18];
  const float* be2 = (const float*)d_in[19];

  char* ws = (char*)d_ws;
  u16*   wbf  = (u16*)(ws + 0);            //  5,242,880 B (10 x 512x512 bf16)
  float* V4   = (float*)(ws + 5242880);    // 14,155,776 B [1728,2048]
  u16*   M1   = (u16*)(ws + 19398656);     // 47,775,744 B [46656,512] bf16
  u16*   M2   = (u16*)(ws + 67174400);     // 47,775,744 B
  float* xnew = (float*)(ws + 114950144);  //  3,538,944 B
  float* x1   = (float*)(ws + 118489088);  //  3,538,944 B
  float* st   = (float*)(ws + 122028032);  // stats
  float* es1 = st;         float* eq1 = st + 729;
  float* es2 = st + 1458;  float* eq2 = st + 2187;
  float* vs1 = st + 2916;  float* vq1 = st + 2943;
  float* vs2 = st + 2970;  float* vq2 = st + 2997;

  float* xout = (float*)d_out;             // [64,27,512]
  float* eo   = (float*)d_out + 884736;    // [64,729,512] final edge (fp32)

  hipMemsetAsync(st, 0, 3024 * sizeof(float), stream);
  convw_k<<<dim3(2560), dim3(256), 0, stream>>>(WA1, WB1, WU1, WV1, WE1, WA2, WB2, WU2, WV2, WE2, wbf);

  // ---- layer 1 ----
  gemm_k<1, 0, 0><<<dim3(16, 27), dim3(256), 0, stream>>>(x, wbf, V4, 2048, nullptr, nullptr, nullptr, nullptr);
  gemm_k<2, 0, 1><<<dim3(2944), dim3(256), 0, stream>>>(edge, wbf + 4 * 262144, nullptr, 0, M1, V4, es1, eq1);
  edge_attn_k<0, 1><<<dim3(1728), dim3(256), 0, stream>>>(M1, edge, M1, es1, eq1, ge1, be1, V4, xnew, vs1, vq1);
  vert_bn_k<<<dim3(864), dim3(256), 0, stream>>>((const float4*)xnew, (const float4*)x, vs1, vq1, gv1, bv1, (float4*)x1);

  // ---- layer 2 ----
  gemm_k<1, 0, 0><<<dim3(16, 27), dim3(256), 0, stream>>>(x1, wbf + 5 * 262144, V4, 2048, nullptr, nullptr, nullptr, nullptr);
  gemm_k<2, 1, 1><<<dim3(2944), dim3(256), 0, stream>>>(M1, wbf + 9 * 262144, nullptr, 0, M2, V4, es2, eq2);
  edge_attn_k<1, 0><<<dim3(1728), dim3(256), 0, stream>>>(M2, M1, eo, es2, eq2, ge2, be2, V4, xnew, vs2, vq2);
  vert_bn_k<<<dim3(864), dim3(256), 0, stream>>>((const float4*)xnew, (const float4*)x1, vs2, vq2, gv2, bv2, (float4*)xout);
}

// Round 5
// 432.301 us; speedup vs baseline: 1.5454x; 1.5454x over previous
//
#include <hip/hip_runtime.h>

typedef unsigned short u16;
typedef unsigned int u32;
typedef __bf16 bf16x8 __attribute__((ext_vector_type(8)));
typedef float f32x4 __attribute__((ext_vector_type(4)));

#define DI __device__ __forceinline__

DI u16 f2bf(float f) {
  union { float f; u32 u; } v; v.f = f;
  return (u16)((v.u + 0x7fffu + ((v.u >> 16) & 1u)) >> 16);
}
DI float bf2f(u16 h) {
  union { u32 u; float f; } v; v.u = ((u32)h) << 16;
  return v.f;
}

// async 16B global->LDS (dest = wave-uniform base + lane*16)
DI void gload_lds16(const void* g, void* l) {
  __builtin_amdgcn_global_load_lds((const __attribute__((address_space(1))) u32*)g,
                                   (__attribute__((address_space(3))) u32*)l, 16, 0, 0);
}

constexpr float INV_M = 1.0f / 32768.0f;  // 1/(B*C)

// ---------------- weight convert: 10 x [512,512] fp32 -> bf16 ----------------
__global__ void convw_k(const float* wa1, const float* wb1, const float* wu1, const float* wv1, const float* we1,
                        const float* wa2, const float* wb2, const float* wu2, const float* wv2, const float* we2,
                        u16* dst) {
  int idx = blockIdx.x * 256 + threadIdx.x;   // group of 4 floats
  int m = idx >> 16;
  int i = (idx & 0xffff) << 2;
  const float* s;
  switch (m) {
    case 0: s = wa1; break; case 1: s = wb1; break; case 2: s = wu1; break;
    case 3: s = wv1; break; case 4: s = we1; break; case 5: s = wa2; break;
    case 6: s = wb2; break; case 7: s = wu2; break; case 8: s = wv2; break;
    default: s = we2; break;
  }
  float4 v = *(const float4*)(s + i);
  ushort4 o;
  o.x = f2bf(v.x); o.y = f2bf(v.y); o.z = f2bf(v.z); o.w = f2bf(v.w);
  *(ushort4*)(dst + ((size_t)m << 18) + i) = o;
}

// ---------------- GEMM: out[m,n] = sum_k A[m,k] * W[n,k] ----------------
// BM=64, BN=32*NT, BK=64, 256 thr (4 waves 2x2), wave tile 32 x 16*NT.
// Software pipeline: W -> LDS double-buffer via global_load_lds issued for tile k+1
// before compute(k) (drain lands at the bottom barrier, hidden by compute);
// A -> VGPR prefetch for k+1 before compute(k), packed to LDS after bottom barrier.
// XOR-swizzled LDS layout (conflict-free); SWZ = XCD-aware 1-D grid remap.
// EPI==1: fp32 store. EPI==2: msg=acc+Vix+Vjx -> bf16 + fused edge BN stats.
template<int EPI, int ABF, int SWZ, int NT>
__global__ __launch_bounds__(256, 4) void gemm_k(
    const void* __restrict__ A_, const u16* __restrict__ W,
    float* __restrict__ outf, int ldout,
    u16* __restrict__ msg, const float* __restrict__ V4,
    float* __restrict__ esum, float* __restrict__ esq) {
  __shared__ __align__(16) u16 lA[64 * 64];            // 8 KB
  __shared__ __align__(16) u16 lW[2][32 * NT * 64];    // 2 x 4KB*NT
  const int tid = threadIdx.x;
  const int lane = tid & 63, wid = tid >> 6;
  const int wm = wid >> 1, wn = wid & 1;
  const int q = lane >> 4, l15 = lane & 15;
  const int lrow8 = lane >> 3, lg = lane & 7;
  const int arow = tid >> 3, ag = tid & 7;             // A stage: rows arow, arow+32

  int rb, cb;
  if (SWZ) {
    int l = blockIdx.x;
    int xcd = l & 7, t = l >> 3;
    cb = t & 3;
    rb = ((t >> 2) << 3) | xcd;
    if (rb >= 729) return;
  } else {
    rb = blockIdx.y; cb = blockIdx.x;
  }

  float4 pAf[2][2];
  uint4 pAb[2];

#define ISSUE_W(buf, k0)                                                                            \
  {                                                                                                 \
    _Pragma("unroll")                                                                               \
    for (int it = 0; it < NT; it++) {                                                               \
      int ch = wid * NT + it;                                                                       \
      int row = ch * 8 + lrow8;                                                                     \
      const u16* src = W + (((size_t)(cb * 32 * NT + row)) << 9) + (k0) + ((lg ^ (row & 7)) << 3);  \
      gload_lds16(src, &lW[buf][ch * 512]);                                                         \
    }                                                                                               \
  }

#define LOAD_A(k0)                                                                                  \
  {                                                                                                 \
    if (ABF) {                                                                                      \
      _Pragma("unroll")                                                                             \
      for (int i = 0; i < 2; i++)                                                                   \
        pAb[i] = *(const uint4*)((const u16*)A_ + (((size_t)(rb * 64 + arow + 32 * i)) << 9) + (k0) + (ag << 3)); \
    } else {                                                                                        \
      _Pragma("unroll")                                                                             \
      for (int i = 0; i < 2; i++) {                                                                 \
        const float* s = (const float*)A_ + (((size_t)(rb * 64 + arow + 32 * i)) << 9) + (k0) + (ag << 3); \
        pAf[i][0] = *(const float4*)s;                                                              \
        pAf[i][1] = *(const float4*)(s + 4);                                                        \
      }                                                                                             \
    }                                                                                               \
  }

#define WRITE_A()                                                                                   \
  {                                                                                                 \
    _Pragma("unroll")                                                                               \
    for (int i = 0; i < 2; i++) {                                                                   \
      int row = arow + 32 * i;                                                                      \
      uint4 p;                                                                                      \
      if (ABF) {                                                                                    \
        p = pAb[i];                                                                                 \
      } else {                                                                                      \
        p.x = f2bf(pAf[i][0].x) | ((u32)f2bf(pAf[i][0].y) << 16);                                   \
        p.y = f2bf(pAf[i][0].z) | ((u32)f2bf(pAf[i][0].w) << 16);                                   \
        p.z = f2bf(pAf[i][1].x) | ((u32)f2bf(pAf[i][1].y) << 16);                                   \
        p.w = f2bf(pAf[i][1].z) | ((u32)f2bf(pAf[i][1].w) << 16);                                   \
      }                                                                                             \
      *(uint4*)(lA + row * 64 + ((ag ^ (row & 7)) << 3)) = p;                                       \
    }                                                                                               \
  }

  f32x4 acc[2][NT];
#pragma unroll
  for (int a = 0; a < 2; a++)
#pragma unroll
    for (int b = 0; b < NT; b++) acc[a][b] = (f32x4){0.f, 0.f, 0.f, 0.f};

  // prologue: tile 0
  LOAD_A(0);
  ISSUE_W(0, 0);
  WRITE_A();

#pragma unroll 2
  for (int kt = 0; kt < 8; kt++) {
    __syncthreads();   // drains tile-kt W (in flight for a full iteration) + makes lA visible
    if (kt < 7) {
      ISSUE_W((kt + 1) & 1, (kt + 1) * 64);
      LOAD_A((kt + 1) * 64);
    }
    const u16* lWc = lW[kt & 1];
#pragma unroll
    for (int ks = 0; ks < 2; ks++) {
      const int gk = ks * 4 + q;
      bf16x8 af[2], wf[NT];
#pragma unroll
      for (int mt = 0; mt < 2; mt++) {
        int r = wm * 32 + mt * 16 + l15;
        af[mt] = *(const bf16x8*)(lA + r * 64 + ((gk ^ (r & 7)) << 3));
      }
#pragma unroll
      for (int nt = 0; nt < NT; nt++) {
        int r = wn * 16 * NT + nt * 16 + l15;
        wf[nt] = *(const bf16x8*)(lWc + r * 64 + ((gk ^ (r & 7)) << 3));
      }
#pragma unroll
      for (int mt = 0; mt < 2; mt++)
#pragma unroll
        for (int nt = 0; nt < NT; nt++)
          acc[mt][nt] = __builtin_amdgcn_mfma_f32_16x16x32_bf16(af[mt], wf[nt], acc[mt][nt], 0, 0, 0);
    }
    __syncthreads();   // all waves done reading lA / lW[kt&1]
    if (kt < 7) WRITE_A();
  }

  if (EPI == 1) {
#pragma unroll
    for (int mt = 0; mt < 2; mt++) {
      int grow0 = rb * 64 + wm * 32 + mt * 16 + q * 4;
#pragma unroll
      for (int nt = 0; nt < NT; nt++) {
        int gcol = cb * 32 * NT + wn * 16 * NT + nt * 16 + l15;
#pragma unroll
        for (int r = 0; r < 4; r++)
          outf[(size_t)(grow0 + r) * ldout + gcol] = acc[mt][nt][r];
      }
    }
  } else {
    // msg = acc + Vix[b,i,:] + Vjx[b,j,:]; row = b*729 + i*27 + j
    float ms[2][4], m2[2][4];
#pragma unroll
    for (int mt = 0; mt < 2; mt++) {
#pragma unroll
      for (int r = 0; r < 4; r++) {
        int grow = rb * 64 + wm * 32 + mt * 16 + q * 4 + r;
        int b = grow / 729;
        int e = grow - b * 729;
        int i = e / 27;
        int j = e - i * 27;
        const float* vix = V4 + (((size_t)(b * 27 + i)) << 11);
        const float* vjx = V4 + (((size_t)(b * 27 + j)) << 11) + 512;
        u16* mrow = msg + (((size_t)grow) << 9);
        float s1 = 0.f, s2 = 0.f;
#pragma unroll
        for (int nt = 0; nt < NT; nt++) {
          int c = cb * 32 * NT + wn * 16 * NT + nt * 16 + l15;
          float m = acc[mt][nt][r] + vix[c] + vjx[c];
          mrow[c] = f2bf(m);
          s1 += m;
          s2 += m * m;
        }
        ms[mt][r] = s1;
        m2[mt][r] = s2;
      }
    }
#pragma unroll
    for (int msk = 1; msk < 16; msk <<= 1) {
#pragma unroll
      for (int mt = 0; mt < 2; mt++)
#pragma unroll
        for (int r = 0; r < 4; r++) {
          ms[mt][r] += __shfl_xor(ms[mt][r], msk);
          m2[mt][r] += __shfl_xor(m2[mt][r], msk);
        }
    }
    __syncthreads();
    float* sm = (float*)lA;
    if (l15 == 0) {
#pragma unroll
      for (int mt = 0; mt < 2; mt++)
#pragma unroll
        for (int r = 0; r < 4; r++) {
          int rib = wm * 32 + mt * 16 + q * 4 + r;
          sm[wn * 64 + rib] = ms[mt][r];
          sm[128 + wn * 64 + rib] = m2[mt][r];
        }
    }
    __syncthreads();
    if (tid < 64) {
      int grow = rb * 64 + tid;
      int e = grow % 729;
      atomicAdd(&esum[e], sm[tid] + sm[64 + tid]);
      atomicAdd(&esq[e], sm[128 + tid] + sm[192 + tid]);
    }
  }
}

// ---------------- fused: eab; eout = ein + relu(bn(msg)); sigmoid+softmax_j; agg; xnew; vstats ----------------
// 256 threads, 2 channels/thread, packed loads.
template<int INBF, int OUTBF>
__global__ __launch_bounds__(256) void edge_attn_k(
    const u16* __restrict__ msg, const void* __restrict__ ein_, void* __restrict__ eout_,
    const float* __restrict__ esum, const float* __restrict__ esq,
    const float* __restrict__ ge, const float* __restrict__ be,
    const float* __restrict__ V4,
    float* __restrict__ xnew, float* __restrict__ vsum, float* __restrict__ vsq) {
  const int bi = blockIdx.x;          // b*27 + i
  const int b = bi / 27, i = bi - b * 27;
  const int t = threadIdx.x;          // channels 2t, 2t+1
  __shared__ float2 sab[27];
  if (t < 27) {
    int e = i * 27 + t;
    float mean = esum[e] * INV_M;
    float var = esq[e] * INV_M - mean * mean;
    float a = ge[e] * rsqrtf(var + 1e-5f);
    sab[t] = make_float2(a, be[e] - mean * a);
  }
  __syncthreads();
  const size_t ebase = (((size_t)(b * 729 + i * 27)) << 9) + 2 * t;
  const u16* einb = (const u16*)ein_;
  const float* einf = (const float*)ein_;
  u16* eoutb = (u16*)eout_;
  float* eoutf = (float*)eout_;
  float t0[27], t1[27];
  float ss0 = 0.f, ss1 = 0.f;
#pragma unroll
  for (int j = 0; j < 27; j++) {
    size_t idx = ebase + (((size_t)j) << 9);
    float2 ab = sab[j];
    u32 mp = *(const u32*)(msg + idx);
    float2 ei;
    if (INBF) {
      u32 ep = *(const u32*)(einb + idx);
      ei = make_float2(bf2f((u16)ep), bf2f((u16)(ep >> 16)));
    } else {
      ei = *(const float2*)(einf + idx);
    }
    float e0 = ei.x + fmaxf(fmaf(ab.x, bf2f((u16)mp), ab.y), 0.f);
    float e1 = ei.y + fmaxf(fmaf(ab.x, bf2f((u16)(mp >> 16)), ab.y), 0.f);
    if (OUTBF) {
      *(u32*)(eoutb + idx) = (u32)f2bf(e0) | ((u32)f2bf(e1) << 16);
    } else {
      *(float2*)(eoutf + idx) = make_float2(e0, e1);
    }
    float x0 = __expf(1.f / (1.f + __expf(-e0)));
    float x1 = __expf(1.f / (1.f + __expf(-e1)));
    ss0 += x0; ss1 += x1;
    t0[j] = x0; t1[j] = x1;
  }
  float a0 = 0.f, a1 = 0.f;
#pragma unroll
  for (int j = 0; j < 27; j++) {
    float2 uj = *(const float2*)(V4 + (((size_t)(b * 27 + j)) << 11) + 1536 + 2 * t);  // Ujx
    a0 = fmaf(t0[j], uj.x, a0);
    a1 = fmaf(t1[j], uj.y, a1);
  }
  float2 ui = *(const float2*)(V4 + (((size_t)(b * 27 + i)) << 11) + 1024 + 2 * t);    // Uix
  float xn0 = ui.x + a0 / (ss0 * 27.f);
  float xn1 = ui.y + a1 / (ss1 * 27.f);
  *(float2*)(xnew + (((size_t)bi) << 9) + 2 * t) = make_float2(xn0, xn1);
  float v = xn0 + xn1, v2 = xn0 * xn0 + xn1 * xn1;
#pragma unroll
  for (int m = 32; m >= 1; m >>= 1) {
    v += __shfl_xor(v, m);
    v2 += __shfl_xor(v2, m);
  }
  __shared__ float red[8];
  int w = t >> 6, ln = t & 63;
  if (ln == 0) { red[w] = v; red[4 + w] = v2; }
  __syncthreads();
  if (t == 0) {
    float s1 = 0.f, s2 = 0.f;
#pragma unroll
    for (int k = 0; k < 4; k++) { s1 += red[k]; s2 += red[4 + k]; }
    atomicAdd(&vsum[i], s1);
    atomicAdd(&vsq[i], s2);
  }
}

// ---------------- x_out = relu(res + bn_v(xnew)), float4 ----------------
__global__ void vert_bn_k(const float4* __restrict__ xnew, const float4* __restrict__ res,
                          const float* __restrict__ vsum, const float* __restrict__ vsq,
                          const float* __restrict__ g, const float* __restrict__ bt,
                          float4* __restrict__ out) {
  int idx = blockIdx.x * 256 + threadIdx.x;   // float4 index, 221184 total
  int i = (idx >> 7) % 27;
  float mean = vsum[i] * INV_M;
  float var = vsq[i] * INV_M - mean * mean;
  float a = g[i] * rsqrtf(var + 1e-5f);
  float bb = bt[i] - mean * a;
  float4 xv = xnew[idx];
  float4 rv = res[idx];
  float4 o;
  o.x = fmaxf(rv.x + fmaf(a, xv.x, bb), 0.f);
  o.y = fmaxf(rv.y + fmaf(a, xv.y, bb), 0.f);
  o.z = fmaxf(rv.z + fmaf(a, xv.z, bb), 0.f);
  o.w = fmaxf(rv.w + fmaf(a, xv.w, bb), 0.f);
  out[idx] = o;
}

extern "C" void kernel_launch(void* const* d_in, const int* in_sizes, int n_in,
                              void* d_out, int out_size, void* d_ws, size_t ws_size,
                              hipStream_t stream) {
  const float* x    = (const float*)d_in[0];
  const float* edge = (const float*)d_in[1];
  const float* WU1 = (const float*)d_in[2];
  const float* WV1 = (const float*)d_in[3];
  const float* WA1 = (const float*)d_in[4];
  const float* WB1 = (const float*)d_in[5];
  const float* WE1 = (const float*)d_in[6];
  const float* WU2 = (const float*)d_in[7];
  const float* WV2 = (const float*)d_in[8];
  const float* WA2 = (const float*)d_in[9];
  const float* WB2 = (const float*)d_in[10];
  const float* WE2 = (const float*)d_in[11];
  const float* gv1 = (const float*)d_in[12];
  const float* bv1 = (const float*)d_in[13];
  const float* ge1 = (const float*)d_in[14];
  const float* be1 = (const float*)d_in[15];
  const float* gv2 = (const float*)d_in[16];
  const float* bv2 = (const float*)d_in[17];
  const float* ge2 = (const float*)d_in[18];
  const float* be2 = (const float*)d_in[19];

  char* ws = (char*)d_ws;
  u16*   wbf  = (u16*)(ws + 0);            //  5,242,880 B (10 x 512x512 bf16)
  float* V4   = (float*)(ws + 5242880);    // 14,155,776 B [1728,2048]
  u16*   M1   = (u16*)(ws + 19398656);     // 47,775,744 B [46656,512] bf16
  u16*   M2   = (u16*)(ws + 67174400);     // 47,775,744 B
  float* xnew = (float*)(ws + 114950144);  //  3,538,944 B
  float* x1   = (float*)(ws + 118489088);  //  3,538,944 B
  float* st   = (float*)(ws + 122028032);  // stats
  float* es1 = st;         float* eq1 = st + 729;
  float* es2 = st + 1458;  float* eq2 = st + 2187;
  float* vs1 = st + 2916;  float* vq1 = st + 2943;
  float* vs2 = st + 2970;  float* vq2 = st + 2997;

  float* xout = (float*)d_out;             // [64,27,512]
  float* eo   = (float*)d_out + 884736;    // [64,729,512] final edge (fp32)

  hipMemsetAsync(st, 0, 3024 * sizeof(float), stream);
  convw_k<<<dim3(2560), dim3(256), 0, stream>>>(WA1, WB1, WU1, WV1, WE1, WA2, WB2, WU2, WV2, WE2, wbf);

  // ---- layer 1 ----
  gemm_k<1, 0, 0, 2><<<dim3(32, 27), dim3(256), 0, stream>>>(x, wbf, V4, 2048, nullptr, nullptr, nullptr, nullptr);
  gemm_k<2, 0, 1, 4><<<dim3(2944), dim3(256), 0, stream>>>(edge, wbf + 4 * 262144, nullptr, 0, M1, V4, es1, eq1);
  edge_attn_k<0, 1><<<dim3(1728), dim3(256), 0, stream>>>(M1, edge, M1, es1, eq1, ge1, be1, V4, xnew, vs1, vq1);
  vert_bn_k<<<dim3(864), dim3(256), 0, stream>>>((const float4*)xnew, (const float4*)x, vs1, vq1, gv1, bv1, (float4*)x1);

  // ---- layer 2 ----
  gemm_k<1, 0, 0, 2><<<dim3(32, 27), dim3(256), 0, stream>>>(x1, wbf + 5 * 262144, V4, 2048, nullptr, nullptr, nullptr, nullptr);
  gemm_k<2, 1, 1, 4><<<dim3(2944), dim3(256), 0, stream>>>(M1, wbf + 9 * 262144, nullptr, 0, M2, V4, es2, eq2);
  edge_attn_k<1, 0><<<dim3(1728), dim3(256), 0, stream>>>(M2, M1, eo, es2, eq2, ge2, be2, V4, xnew, vs2, vq2);
  vert_bn_k<<<dim3(864), dim3(256), 0, stream>>>((const float4*)xnew, (const float4*)x1, vs2, vq2, gv2, bv2, (float4*)xout);
}